// Round 10
// baseline (2388.529 us; speedup 1.0000x reference)
//
#include <hip/hip_runtime.h>

#define NN 50000
#define NE 800000
#define CC 128
#define SLAB (NN * CC)
#define BN_EPS 1e-5f
#define PAD 132

typedef __attribute__((ext_vector_type(8))) short bf16x8;
typedef __attribute__((ext_vector_type(4))) float f32x4;
typedef unsigned short ushort_t;
typedef unsigned int uint_t;

__device__ inline ushort_t f2bf(float v) {
  unsigned u = __builtin_bit_cast(unsigned, v);
  unsigned r = u + 0x7FFFu + ((u >> 16) & 1u);
  return (ushort_t)(r >> 16);
}
__device__ inline float bf2f(unsigned lo16) { return __builtin_bit_cast(float, lo16 << 16); }

// ---------------- utility ----------------
__global__ void zero_int_kernel(int* __restrict__ p, int n) {
  int i = blockIdx.x * blockDim.x + threadIdx.x;
  if (i < n) p[i] = 0;
}

// ---------------- CSR build ----------------
__global__ void count_kernel(const int* __restrict__ dst, int* __restrict__ counts) {
  int e = blockIdx.x * blockDim.x + threadIdx.x;
  if (e < NE) atomicAdd(&counts[dst[e]], 1);
}

__global__ void scan1_kernel(const int* __restrict__ counts, int* __restrict__ excl,
                             int* __restrict__ blocksum) {
  __shared__ int s[256];
  int t = threadIdx.x;
  int i = blockIdx.x * 256 + t;
  int v = (i < NN) ? counts[i] : 0;
  s[t] = v;
  for (int off = 1; off < 256; off <<= 1) {
    __syncthreads();
    int add = (t >= off) ? s[t - off] : 0;
    __syncthreads();
    s[t] += add;
  }
  __syncthreads();
  if (i < NN) excl[i] = s[t] - v;
  if (t == 255) blocksum[blockIdx.x] = s[255];
}

__global__ void scan2_kernel(int* __restrict__ blocksum, int nb) {
  __shared__ int s[256];
  int t = threadIdx.x;
  int v = (t < nb) ? blocksum[t] : 0;
  s[t] = v;
  for (int off = 1; off < 256; off <<= 1) {
    __syncthreads();
    int add = (t >= off) ? s[t - off] : 0;
    __syncthreads();
    s[t] += add;
  }
  __syncthreads();
  if (t < nb) blocksum[t] = s[t] - v;
}

__global__ void scan3_kernel(int* __restrict__ excl, const int* __restrict__ blocksum) {
  int i = blockIdx.x * 256 + threadIdx.x;
  if (i < NN) excl[i] += blocksum[blockIdx.x];
}

// bucket2[e'] = (src, dst) grouped by dst
__global__ void fill_kernel(const int* __restrict__ src, const int* __restrict__ dst,
                            const int* __restrict__ starts, int* __restrict__ fill,
                            int2* __restrict__ bucket2) {
  int e = blockIdx.x * blockDim.x + threadIdx.x;
  if (e < NE) {
    int d = dst[e];
    int pos = atomicAdd(&fill[d], 1);
    bucket2[starts[d] + pos] = make_int2(src[e], d);
  }
}

// ---------------- W prep: split + pack into per-(ks,nt) 64-lane fragments ----------------
__global__ void prep_w_kernel(const float* __restrict__ fh_W, const float* __restrict__ W1,
                              const float* __restrict__ W2, short* __restrict__ whi,
                              short* __restrict__ wlo) {
  int m = blockIdx.x;
  const float* src = (m == 0) ? fh_W : ((m <= 3) ? W1 + (m - 1) * CC * CC : W2 + (m - 4) * CC * CC);
  short* hi = whi + m * CC * CC;
  short* lo = wlo + m * CC * CC;
  for (int it = 0; it < 64; ++it) {
    int idx = it * 256 + threadIdx.x;  // 0..16383
    int j = idx & 7;
    int l = (idx >> 3) & 63;
    int nt = (idx >> 9) & 7;
    int ks = idx >> 12;
    int n = nt * 16 + (l & 15);
    int k = ks * 32 + ((l >> 4) << 3) + j;
    float v = src[k * CC + n];
    unsigned u = __builtin_bit_cast(unsigned, v);
    unsigned short h = (unsigned short)(u >> 16);
    float hf = __builtin_bit_cast(float, ((unsigned)h) << 16);
    float r = v - hf;
    unsigned ur = __builtin_bit_cast(unsigned, r);
    hi[idx] = (short)h;
    lo[idx] = (short)(ur >> 16);
  }
}

// ---------------- GEMM0 (no LDS): out = x @ fh_W + b; fp32 slab + linear h16 ----------------
__global__ __launch_bounds__(256) void gemm0_kernel(
    const float* __restrict__ A, const short* __restrict__ Wp_hi, const short* __restrict__ Wp_lo,
    const float* __restrict__ bias, float* __restrict__ out, ushort_t* __restrict__ h16) {
  const int t = threadIdx.x;
  const int l = t & 63;
  const int wv = t >> 6;
  const int m0 = blockIdx.x * 64 + wv * 16;
  const int row = m0 + (l & 15);
  const int kg = (l >> 4) * 8;

  f32x4 acc[8];
#pragma unroll
  for (int i = 0; i < 8; ++i) acc[i] = (f32x4){0.f, 0.f, 0.f, 0.f};

#pragma unroll
  for (int ks = 0; ks < 4; ++ks) {
    float av[8];
    if (row < NN) {
      const float* ap = &A[row * CC + ks * 32 + kg];
      float4 v0 = *(const float4*)ap;
      float4 v1 = *(const float4*)(ap + 4);
      av[0] = v0.x; av[1] = v0.y; av[2] = v0.z; av[3] = v0.w;
      av[4] = v1.x; av[5] = v1.y; av[6] = v1.z; av[7] = v1.w;
    } else {
#pragma unroll
      for (int i = 0; i < 8; ++i) av[i] = 0.f;
    }
    bf16x8 ah, al;
#pragma unroll
    for (int i = 0; i < 8; ++i) {
      unsigned u = __builtin_bit_cast(unsigned, av[i]);
      unsigned short hbits = (unsigned short)(u >> 16);
      float hf = __builtin_bit_cast(float, ((unsigned)hbits) << 16);
      float r = av[i] - hf;
      unsigned ur = __builtin_bit_cast(unsigned, r);
      ah[i] = (short)hbits;
      al[i] = (short)(ur >> 16);
    }
#pragma unroll
    for (int nt = 0; nt < 8; ++nt) {
      const int base = (ks * 8 + nt) * 512 + l * 8;
      bf16x8 wh = *(const bf16x8*)&Wp_hi[base];
      bf16x8 wl = *(const bf16x8*)&Wp_lo[base];
      acc[nt] = __builtin_amdgcn_mfma_f32_16x16x32_bf16(ah, wh, acc[nt], 0, 0, 0);
      acc[nt] = __builtin_amdgcn_mfma_f32_16x16x32_bf16(al, wh, acc[nt], 0, 0, 0);
      acc[nt] = __builtin_amdgcn_mfma_f32_16x16x32_bf16(ah, wl, acc[nt], 0, 0, 0);
    }
  }

  const int rbase = m0 + (l >> 4) * 4;
  const int cn = l & 15;
#pragma unroll
  for (int nt = 0; nt < 8; ++nt) {
    int c = nt * 16 + cn;
    float bv = bias[c];
#pragma unroll
    for (int r = 0; r < 4; ++r) {
      int rr = rbase + r;
      if (rr < NN) {
        float v = acc[nt][r] + bv;
        out[rr * CC + c] = v;
        h16[rr * CC + c] = f2bf(v);
      }
    }
  }
}

// ---------------- fused edge-parallel gather + GEMM1 ----------------
// Block owns rows [64b, 64b+64). Phase 1: seed LDS fp32 tile with self rows; all 4 waves
// sweep the block's contiguous CSR edge range; each 16-lane group loads one neighbor row
// (256 B) and atomicAdds into the tile (ds_add_f32). Phase 2: MFMA from tile, bf16 out + stats.
__global__ __launch_bounds__(256) void fused1_kernel(
    const ushort_t* __restrict__ h16, const int* __restrict__ starts,
    const int2* __restrict__ bucket2, const short* __restrict__ Wp_hi,
    const short* __restrict__ Wp_lo, const float* __restrict__ bias,
    ushort_t* __restrict__ tmp16, float* __restrict__ stats_out) {
  __shared__ float tile[64 * PAD];
  __shared__ float sred[2 * CC];
  const int t = threadIdx.x;
  const int l = t & 63;
  const int wv = t >> 6;
  const int q = l >> 4;
  const int j16 = l & 15;
  const int rowbase = blockIdx.x * 64;
  sred[t] = 0.f;

  // phase 0: seed tile with self rows (coalesced 16B loads)
#pragma unroll
  for (int i = 0; i < 4; ++i) {
    int f = i * 256 + t;       // 0..1023
    int r = f >> 4;            // row 0..63
    int c8 = (f & 15) * 8;     // chan 0..120
    int rg = rowbase + r;
    float vals[8];
    if (rg < NN) {
      uint4 u = *(const uint4*)&h16[rg * CC + c8];
      vals[0] = bf2f(u.x & 0xFFFFu); vals[1] = bf2f(u.x >> 16);
      vals[2] = bf2f(u.y & 0xFFFFu); vals[3] = bf2f(u.y >> 16);
      vals[4] = bf2f(u.z & 0xFFFFu); vals[5] = bf2f(u.z >> 16);
      vals[6] = bf2f(u.w & 0xFFFFu); vals[7] = bf2f(u.w >> 16);
    } else {
#pragma unroll
      for (int j = 0; j < 8; ++j) vals[j] = 0.f;
    }
#pragma unroll
    for (int j = 0; j < 8; ++j) tile[r * PAD + c8 + j] = vals[j];
  }
  __syncthreads();

  // phase 1: edge-parallel accumulate
  const int e0 = starts[rowbase];
  const int e1 = (rowbase + 64 < NN) ? starts[rowbase + 64] : NE;
  for (int eb = e0 + wv * 64; eb < e1; eb += 256) {
    int m = e1 - eb;
    if (m > 64) m = 64;
    int2 ed = (l < m) ? bucket2[eb + l] : make_int2(0, rowbase);
    for (int jj = 0; jj < m; jj += 4) {
      int i = jj + q;
      int ok = (i < m);
      int sel = ok ? i : 0;
      int sr = __shfl(ed.x, sel);
      int dr = __shfl(ed.y, sel);
      if (ok) {
        uint4 u = *(const uint4*)&h16[sr * CC + j16 * 8];
        float* d = &tile[(dr - rowbase) * PAD + j16 * 8];
        atomicAdd(&d[0], bf2f(u.x & 0xFFFFu));
        atomicAdd(&d[1], bf2f(u.x >> 16));
        atomicAdd(&d[2], bf2f(u.y & 0xFFFFu));
        atomicAdd(&d[3], bf2f(u.y >> 16));
        atomicAdd(&d[4], bf2f(u.z & 0xFFFFu));
        atomicAdd(&d[5], bf2f(u.z >> 16));
        atomicAdd(&d[6], bf2f(u.w & 0xFFFFu));
        atomicAdd(&d[7], bf2f(u.w >> 16));
      }
    }
  }
  __syncthreads();

  // phase 2: MFMA from tile
  f32x4 acc[8];
#pragma unroll
  for (int i = 0; i < 8; ++i) acc[i] = (f32x4){0.f, 0.f, 0.f, 0.f};
  const int arow = (wv * 16 + (l & 15)) * PAD;
  const int kg = q * 8;

#pragma unroll
  for (int ks = 0; ks < 4; ++ks) {
    const float* ap = &tile[arow + ks * 32 + kg];
    bf16x8 ah;
#pragma unroll
    for (int i = 0; i < 8; ++i) ah[i] = (short)f2bf(ap[i]);
#pragma unroll
    for (int nt = 0; nt < 8; ++nt) {
      const int base = (ks * 8 + nt) * 512 + l * 8;
      bf16x8 wh = *(const bf16x8*)&Wp_hi[base];
      bf16x8 wl = *(const bf16x8*)&Wp_lo[base];
      acc[nt] = __builtin_amdgcn_mfma_f32_16x16x32_bf16(ah, wh, acc[nt], 0, 0, 0);
      acc[nt] = __builtin_amdgcn_mfma_f32_16x16x32_bf16(ah, wl, acc[nt], 0, 0, 0);
    }
  }

  // epilogue: bias, bf16 store, stats
  const int rbase = rowbase + wv * 16 + (l >> 4) * 4;
  const int cn = l & 15;
#pragma unroll
  for (int nt = 0; nt < 8; ++nt) {
    int c = nt * 16 + cn;
    float bv = bias[c];
    float s = 0.f, qq = 0.f;
#pragma unroll
    for (int r = 0; r < 4; ++r) {
      int rr = rbase + r;
      if (rr < NN) {
        float v = acc[nt][r] + bv;
        tmp16[rr * CC + c] = f2bf(v);
        s += v; qq += v * v;
      }
    }
    s += __shfl_xor(s, 16); s += __shfl_xor(s, 32);
    qq += __shfl_xor(qq, 16); qq += __shfl_xor(qq, 32);
    if (q == 0) {
      atomicAdd(&sred[c], s);
      atomicAdd(&sred[CC + c], qq);
    }
  }
  __syncthreads();
  atomicAdd(&stats_out[t], sred[t]);
}

// ---------------- GEMM2: tmp16 = bf16(relu(BN1(tmp16)) @ W2 + b2) in-place, stats2 ----------------
__global__ __launch_bounds__(256) void gemm2_kernel(
    ushort_t* __restrict__ tmp16, const short* __restrict__ Wp_hi,
    const short* __restrict__ Wp_lo, const float* __restrict__ bias,
    const float* __restrict__ stats_in, const float* __restrict__ g,
    const float* __restrict__ be, float* __restrict__ stats_out) {
  __shared__ float sred[2 * CC];
  const int t = threadIdx.x;
  const int l = t & 63;
  const int wv = t >> 6;
  const int m0 = blockIdx.x * 64 + wv * 16;
  const int row = m0 + (l & 15);
  const int kg = (l >> 4) * 8;
  sred[t] = 0.f;

  f32x4 acc[8];
#pragma unroll
  for (int i = 0; i < 8; ++i) acc[i] = (f32x4){0.f, 0.f, 0.f, 0.f};

#pragma unroll
  for (int ks = 0; ks < 4; ++ks) {
    bf16x8 ah;
    if (row < NN) {
      bf16x8 raw = *(const bf16x8*)&tmp16[row * CC + ks * 32 + kg];
#pragma unroll
      for (int i = 0; i < 8; ++i) {
        int c = ks * 32 + kg + i;
        float mu = stats_in[c] * (1.0f / NN);
        float var = fmaxf(stats_in[CC + c] * (1.0f / NN) - mu * mu, 0.f);
        float a = g[c] * rsqrtf(var + BN_EPS);
        float d = fmaf(-mu, a, be[c]);
        float v = bf2f((unsigned)(ushort_t)raw[i]);
        v = fmaxf(fmaf(v, a, d), 0.f);
        ah[i] = (short)f2bf(v);
      }
    } else {
#pragma unroll
      for (int i = 0; i < 8; ++i) ah[i] = 0;
    }
#pragma unroll
    for (int nt = 0; nt < 8; ++nt) {
      const int base = (ks * 8 + nt) * 512 + l * 8;
      bf16x8 wh = *(const bf16x8*)&Wp_hi[base];
      bf16x8 wl = *(const bf16x8*)&Wp_lo[base];
      acc[nt] = __builtin_amdgcn_mfma_f32_16x16x32_bf16(ah, wh, acc[nt], 0, 0, 0);
      acc[nt] = __builtin_amdgcn_mfma_f32_16x16x32_bf16(ah, wl, acc[nt], 0, 0, 0);
    }
  }

  __syncthreads();
  const int rbase = m0 + (l >> 4) * 4;
  const int cn = l & 15;
#pragma unroll
  for (int nt = 0; nt < 8; ++nt) {
    int c = nt * 16 + cn;
    float bv = bias[c];
    float s = 0.f, qq = 0.f;
#pragma unroll
    for (int r = 0; r < 4; ++r) {
      int rr = rbase + r;
      if (rr < NN) {
        float v = acc[nt][r] + bv;
        tmp16[rr * CC + c] = f2bf(v);
        s += v; qq += v * v;
      }
    }
    s += __shfl_xor(s, 16); s += __shfl_xor(s, 32);
    qq += __shfl_xor(qq, 16); qq += __shfl_xor(qq, 32);
    if ((l >> 4) == 0) {
      atomicAdd(&sred[c], s);
      atomicAdd(&sred[CC + c], qq);
    }
  }
  __syncthreads();
  atomicAdd(&stats_out[t], sred[t]);
}

// ---------------- apply: BN2(inline)+relu -> fp32 out slab + linear h16 ----------------
// thread = (node, 32-ch quarter): 4 consecutive threads cover one node (coalesced).
// BN coefficients cached in LDS once per block.
__global__ __launch_bounds__(256) void apply_kernel(
    const ushort_t* __restrict__ t2, const float* __restrict__ stats2,
    const float* __restrict__ g2, const float* __restrict__ be2,
    float* __restrict__ outslab, ushort_t* __restrict__ h16) {
  __shared__ float bn[2 * CC];
  const int t = threadIdx.x;
  if (t < CC) {
    float mu = stats2[t] * (1.0f / NN);
    float var = fmaxf(stats2[CC + t] * (1.0f / NN) - mu * mu, 0.f);
    float a = g2[t] * rsqrtf(var + BN_EPS);
    bn[t] = a;
    bn[CC + t] = fmaf(-mu, a, be2[t]);
  }
  __syncthreads();

  const int idx = blockIdx.x * 256 + t;
  const int node = idx >> 2;
  if (node >= NN) return;
  const int c0 = (idx & 3) * 32;

  const uint4* tp = (const uint4*)(t2 + node * CC + c0);  // 64 B
  uint4 r[4];
#pragma unroll
  for (int i = 0; i < 4; ++i) r[i] = tp[i];

  float vo[32];
#pragma unroll
  for (int i = 0; i < 4; ++i) {
    unsigned ws[4] = {r[i].x, r[i].y, r[i].z, r[i].w};
#pragma unroll
    for (int j = 0; j < 4; ++j) {
      vo[i * 8 + 2 * j] = bf2f(ws[j] & 0xFFFFu);
      vo[i * 8 + 2 * j + 1] = bf2f(ws[j] >> 16);
    }
  }
#pragma unroll
  for (int j = 0; j < 32; ++j) {
    int c = c0 + j;
    vo[j] = fmaxf(fmaf(vo[j], bn[c], bn[CC + c]), 0.f);
  }
  float* op = &outslab[node * CC + c0];
#pragma unroll
  for (int j = 0; j < 8; ++j) {
    float4 v = make_float4(vo[4 * j], vo[4 * j + 1], vo[4 * j + 2], vo[4 * j + 3]);
    *(float4*)&op[4 * j] = v;
  }
  if (h16) {
    uint4* hp = (uint4*)(h16 + node * CC + c0);
#pragma unroll
    for (int i = 0; i < 4; ++i) {
      uint4 o;
      o.x = (unsigned)f2bf(vo[i * 8 + 0]) | ((unsigned)f2bf(vo[i * 8 + 1]) << 16);
      o.y = (unsigned)f2bf(vo[i * 8 + 2]) | ((unsigned)f2bf(vo[i * 8 + 3]) << 16);
      o.z = (unsigned)f2bf(vo[i * 8 + 4]) | ((unsigned)f2bf(vo[i * 8 + 5]) << 16);
      o.w = (unsigned)f2bf(vo[i * 8 + 6]) | ((unsigned)f2bf(vo[i * 8 + 7]) << 16);
      hp[i] = o;
    }
  }
}

// ---------------- launch ----------------
extern "C" void kernel_launch(void* const* d_in, const int* in_sizes, int n_in,
                              void* d_out, int out_size, void* d_ws, size_t ws_size,
                              hipStream_t stream) {
  const float* x    = (const float*)d_in[0];
  const int*   edge = (const int*)d_in[1];
  const float* fh_W = (const float*)d_in[3];
  const float* fh_b = (const float*)d_in[4];
  const float* W1   = (const float*)d_in[5];
  const float* b1   = (const float*)d_in[6];
  const float* g1   = (const float*)d_in[7];
  const float* be1  = (const float*)d_in[8];
  const float* W2   = (const float*)d_in[9];
  const float* b2   = (const float*)d_in[10];
  const float* g2   = (const float*)d_in[11];
  const float* be2  = (const float*)d_in[12];
  float* out = (float*)d_out;

  const int* src = edge;
  const int* dst = edge + NE;

  // workspace layout: [counts 50048][fill 50048][stats 1536f] zeroed together
  int* counts   = (int*)d_ws;
  int* fill     = counts + 50048;
  float* stats  = (float*)(fill + 50048);          // 6 x 256 floats
  int* starts   = (int*)(stats + 1536);            // 50048
  int* blocksum = starts + 50048;                  // 256
  int2* bucket2 = (int2*)(blocksum + 256);         // 800000 pairs (6.4 MB)
  short* whi    = (short*)(bucket2 + NE);          // 7*16384
  short* wlo    = whi + 7 * CC * CC;               // 7*16384
  ushort_t* h16 = (ushort_t*)(wlo + 7 * CC * CC);  // SLAB bf16 (linear)
  ushort_t* tmp16 = h16 + SLAB;                    // SLAB bf16 (linear)

  // CSR build + stats zero
  zero_int_kernel<<<(101632 + 255) / 256, 256, 0, stream>>>(counts, 101632);
  count_kernel<<<NE / 256, 256, 0, stream>>>(dst, counts);
  scan1_kernel<<<196, 256, 0, stream>>>(counts, starts, blocksum);
  scan2_kernel<<<1, 256, 0, stream>>>(blocksum, 196);
  scan3_kernel<<<196, 256, 0, stream>>>(starts, blocksum);
  fill_kernel<<<NE / 256, 256, 0, stream>>>(src, dst, starts, fill, bucket2);

  // weight prep
  prep_w_kernel<<<7, 256, 0, stream>>>(fh_W, W1, W2, whi, wlo);

  // first head
  gemm0_kernel<<<782, 256, 0, stream>>>(x, whi, wlo, fh_b, out, h16);

  for (int ly = 0; ly < 3; ++ly) {
    float* stats1 = stats + (ly * 2) * 256;
    float* stats2 = stats + (ly * 2 + 1) * 256;
    fused1_kernel<<<782, 256, 0, stream>>>(
        h16, starts, bucket2, whi + (1 + ly) * CC * CC, wlo + (1 + ly) * CC * CC,
        b1 + ly * CC, tmp16, stats1);
    gemm2_kernel<<<782, 256, 0, stream>>>(
        tmp16, whi + (4 + ly) * CC * CC, wlo + (4 + ly) * CC * CC, b2 + ly * CC,
        stats1, g1 + ly * CC, be1 + ly * CC, stats2);
    apply_kernel<<<782, 256, 0, stream>>>(
        tmp16, stats2, g2 + ly * CC, be2 + ly * CC, out + (ly + 1) * SLAB,
        (ly < 2) ? h16 : (ushort_t*)nullptr);
  }
}

// Round 12
// 483.710 us; speedup vs baseline: 4.9379x; 4.9379x over previous
//
#include <hip/hip_runtime.h>

#define NN 50000
#define NE 800000
#define CC 128
#define SLAB (NN * CC)
#define BN_EPS 1e-5f

typedef __attribute__((ext_vector_type(8))) short bf16x8;
typedef __attribute__((ext_vector_type(4))) float f32x4;
typedef unsigned short ushort_t;
typedef unsigned int uint_t;

__device__ inline ushort_t f2bf(float v) {
  unsigned u = __builtin_bit_cast(unsigned, v);
  unsigned r = u + 0x7FFFu + ((u >> 16) & 1u);
  return (ushort_t)(r >> 16);
}
__device__ inline float bf2f(unsigned lo16) { return __builtin_bit_cast(float, lo16 << 16); }

// ---------------- utility ----------------
__global__ void zero_int_kernel(int* __restrict__ p, int n) {
  int i = blockIdx.x * blockDim.x + threadIdx.x;
  if (i < n) p[i] = 0;
}

// ---------------- CSR build ----------------
__global__ void count_kernel(const int* __restrict__ dst, int* __restrict__ counts) {
  int e = blockIdx.x * blockDim.x + threadIdx.x;
  if (e < NE) atomicAdd(&counts[dst[e]], 1);
}

__global__ void scan1_kernel(const int* __restrict__ counts, int* __restrict__ excl,
                             int* __restrict__ blocksum) {
  __shared__ int s[256];
  int t = threadIdx.x;
  int i = blockIdx.x * 256 + t;
  int v = (i < NN) ? counts[i] : 0;
  s[t] = v;
  for (int off = 1; off < 256; off <<= 1) {
    __syncthreads();
    int add = (t >= off) ? s[t - off] : 0;
    __syncthreads();
    s[t] += add;
  }
  __syncthreads();
  if (i < NN) excl[i] = s[t] - v;
  if (t == 255) blocksum[blockIdx.x] = s[255];
}

__global__ void scan2_kernel(int* __restrict__ blocksum, int nb) {
  __shared__ int s[256];
  int t = threadIdx.x;
  int v = (t < nb) ? blocksum[t] : 0;
  s[t] = v;
  for (int off = 1; off < 256; off <<= 1) {
    __syncthreads();
    int add = (t >= off) ? s[t - off] : 0;
    __syncthreads();
    s[t] += add;
  }
  __syncthreads();
  if (t < nb) blocksum[t] = s[t] - v;
}

__global__ void scan3_kernel(int* __restrict__ excl, const int* __restrict__ blocksum) {
  int i = blockIdx.x * 256 + threadIdx.x;
  if (i < NN) excl[i] += blocksum[blockIdx.x];
}

__global__ void fill_kernel(const int* __restrict__ src, const int* __restrict__ dst,
                            const int* __restrict__ starts, int* __restrict__ fill,
                            int* __restrict__ bucket) {
  int e = blockIdx.x * blockDim.x + threadIdx.x;
  if (e < NE) {
    int d = dst[e];
    int pos = atomicAdd(&fill[d], 1);
    bucket[starts[d] + pos] = src[e];
  }
}

// ---------------- W prep: split + pack into per-(ks,nt) 64-lane fragments ----------------
__global__ void prep_w_kernel(const float* __restrict__ fh_W, const float* __restrict__ W1,
                              const float* __restrict__ W2, short* __restrict__ whi,
                              short* __restrict__ wlo) {
  int m = blockIdx.x;
  const float* src = (m == 0) ? fh_W : ((m <= 3) ? W1 + (m - 1) * CC * CC : W2 + (m - 4) * CC * CC);
  short* hi = whi + m * CC * CC;
  short* lo = wlo + m * CC * CC;
  for (int it = 0; it < 64; ++it) {
    int idx = it * 256 + threadIdx.x;  // 0..16383
    int j = idx & 7;
    int l = (idx >> 3) & 63;
    int nt = (idx >> 9) & 7;
    int ks = idx >> 12;
    int n = nt * 16 + (l & 15);
    int k = ks * 32 + ((l >> 4) << 3) + j;
    float v = src[k * CC + n];
    unsigned u = __builtin_bit_cast(unsigned, v);
    unsigned short h = (unsigned short)(u >> 16);
    float hf = __builtin_bit_cast(float, ((unsigned)h) << 16);
    float r = v - hf;
    unsigned ur = __builtin_bit_cast(unsigned, r);
    hi[idx] = (short)h;
    lo[idx] = (short)(ur >> 16);
  }
}

// ---------------- GEMM0 (no LDS): out = x @ fh_W + b; fp32 slab + linear h16 ----------------
__global__ __launch_bounds__(256) void gemm0_kernel(
    const float* __restrict__ A, const short* __restrict__ Wp_hi, const short* __restrict__ Wp_lo,
    const float* __restrict__ bias, float* __restrict__ out, ushort_t* __restrict__ h16) {
  const int t = threadIdx.x;
  const int l = t & 63;
  const int wv = t >> 6;
  const int m0 = blockIdx.x * 64 + wv * 16;
  const int row = m0 + (l & 15);
  const int kg = (l >> 4) * 8;

  f32x4 acc[8];
#pragma unroll
  for (int i = 0; i < 8; ++i) acc[i] = (f32x4){0.f, 0.f, 0.f, 0.f};

#pragma unroll
  for (int ks = 0; ks < 4; ++ks) {
    float av[8];
    if (row < NN) {
      const float* ap = &A[row * CC + ks * 32 + kg];
      float4 v0 = *(const float4*)ap;
      float4 v1 = *(const float4*)(ap + 4);
      av[0] = v0.x; av[1] = v0.y; av[2] = v0.z; av[3] = v0.w;
      av[4] = v1.x; av[5] = v1.y; av[6] = v1.z; av[7] = v1.w;
    } else {
#pragma unroll
      for (int i = 0; i < 8; ++i) av[i] = 0.f;
    }
    bf16x8 ah, al;
#pragma unroll
    for (int i = 0; i < 8; ++i) {
      unsigned u = __builtin_bit_cast(unsigned, av[i]);
      unsigned short hbits = (unsigned short)(u >> 16);
      float hf = __builtin_bit_cast(float, ((unsigned)hbits) << 16);
      float r = av[i] - hf;
      unsigned ur = __builtin_bit_cast(unsigned, r);
      ah[i] = (short)hbits;
      al[i] = (short)(ur >> 16);
    }
#pragma unroll
    for (int nt = 0; nt < 8; ++nt) {
      const int base = (ks * 8 + nt) * 512 + l * 8;
      bf16x8 wh = *(const bf16x8*)&Wp_hi[base];
      bf16x8 wl = *(const bf16x8*)&Wp_lo[base];
      acc[nt] = __builtin_amdgcn_mfma_f32_16x16x32_bf16(ah, wh, acc[nt], 0, 0, 0);
      acc[nt] = __builtin_amdgcn_mfma_f32_16x16x32_bf16(al, wh, acc[nt], 0, 0, 0);
      acc[nt] = __builtin_amdgcn_mfma_f32_16x16x32_bf16(ah, wl, acc[nt], 0, 0, 0);
    }
  }

  const int rbase = m0 + (l >> 4) * 4;
  const int cn = l & 15;
#pragma unroll
  for (int nt = 0; nt < 8; ++nt) {
    int c = nt * 16 + cn;
    float bv = bias[c];
#pragma unroll
    for (int r = 0; r < 4; ++r) {
      int rr = rbase + r;
      if (rr < NN) {
        float v = acc[nt][r] + bv;
        out[rr * CC + c] = v;
        h16[rr * CC + c] = f2bf(v);
      }
    }
  }
}

// ---------------- gather v4: agg16 = bf16(h + sum_nb h) ----------------
// Wave per node; two half-wave groups (32 lanes, uint2/lane = full 256B row per load).
// Half h handles neighbors i === h (mod 2). ALL loop/if bounds are wave-uniform (depend
// only on nb), so every __shfl is convergent; lane index for shfl always < nb.
// Typical degree-16 node: one unconditional 16-batch = 8 independent loads in flight.
__global__ __launch_bounds__(256) void gather_kernel(
    const ushort_t* __restrict__ h16, const int* __restrict__ starts,
    const int* __restrict__ counts, const int* __restrict__ bucket,
    ushort_t* __restrict__ agg16) {
  const int t = threadIdx.x;
  const int node = blockIdx.x * 4 + (t >> 6);
  const int l = t & 63;
  const int h = l >> 5;        // half id
  const int j8 = l & 31;       // uint2 slot within row
  const uint2* tbl = (const uint2*)h16;

  float a0, a1, a2, a3;
  if (h == 0) {
    uint2 u = tbl[node * 32 + j8];
    a0 = bf2f(u.x & 0xFFFFu); a1 = bf2f(u.x >> 16);
    a2 = bf2f(u.y & 0xFFFFu); a3 = bf2f(u.y >> 16);
  } else {
    a0 = a1 = a2 = a3 = 0.f;
  }

  const int s = starts[node];
  const int n = counts[node];
  for (int base = 0; base < n; base += 64) {
    const int nb = min(n - base, 64);
    const int idx = (l < nb) ? bucket[s + base + l] : 0;
    int jj = 0;
    for (; jj + 16 <= nb; jj += 16) {  // 8 rows per half, all valid
      int sr[8];
#pragma unroll
      for (int k = 0; k < 8; ++k) sr[k] = __shfl(idx, jj + 2 * k + h);
      uint2 u[8];
#pragma unroll
      for (int k = 0; k < 8; ++k) u[k] = tbl[sr[k] * 32 + j8];
#pragma unroll
      for (int k = 0; k < 8; ++k) {
        a0 += bf2f(u[k].x & 0xFFFFu); a1 += bf2f(u[k].x >> 16);
        a2 += bf2f(u[k].y & 0xFFFFu); a3 += bf2f(u[k].y >> 16);
      }
    }
    if (jj + 8 <= nb) {                // 4 rows per half
      int sr[4];
#pragma unroll
      for (int k = 0; k < 4; ++k) sr[k] = __shfl(idx, jj + 2 * k + h);
      uint2 u[4];
#pragma unroll
      for (int k = 0; k < 4; ++k) u[k] = tbl[sr[k] * 32 + j8];
#pragma unroll
      for (int k = 0; k < 4; ++k) {
        a0 += bf2f(u[k].x & 0xFFFFu); a1 += bf2f(u[k].x >> 16);
        a2 += bf2f(u[k].y & 0xFFFFu); a3 += bf2f(u[k].y >> 16);
      }
      jj += 8;
    }
    if (jj + 4 <= nb) {                // 2 rows per half
      int sr0 = __shfl(idx, jj + h);
      int sr1 = __shfl(idx, jj + 2 + h);
      uint2 u0 = tbl[sr0 * 32 + j8];
      uint2 u1 = tbl[sr1 * 32 + j8];
      a0 += bf2f(u0.x & 0xFFFFu) + bf2f(u1.x & 0xFFFFu);
      a1 += bf2f(u0.x >> 16) + bf2f(u1.x >> 16);
      a2 += bf2f(u0.y & 0xFFFFu) + bf2f(u1.y & 0xFFFFu);
      a3 += bf2f(u0.y >> 16) + bf2f(u1.y >> 16);
      jj += 4;
    }
    if (jj + 2 <= nb) {                // 1 row per half
      int sr = __shfl(idx, jj + h);
      uint2 u = tbl[sr * 32 + j8];
      a0 += bf2f(u.x & 0xFFFFu); a1 += bf2f(u.x >> 16);
      a2 += bf2f(u.y & 0xFFFFu); a3 += bf2f(u.y >> 16);
      jj += 2;
    }
    if (jj < nb) {                     // last row, half 0 only (shfl still convergent)
      int sr = __shfl(idx, jj);
      if (h == 0) {
        uint2 u = tbl[sr * 32 + j8];
        a0 += bf2f(u.x & 0xFFFFu); a1 += bf2f(u.x >> 16);
        a2 += bf2f(u.y & 0xFFFFu); a3 += bf2f(u.y >> 16);
      }
    }
  }
  a0 += __shfl_xor(a0, 32);
  a1 += __shfl_xor(a1, 32);
  a2 += __shfl_xor(a2, 32);
  a3 += __shfl_xor(a3, 32);
  if (h == 0) {
    uint2 o;
    o.x = (uint_t)f2bf(a0) | ((uint_t)f2bf(a1) << 16);
    o.y = (uint_t)f2bf(a2) | ((uint_t)f2bf(a3) << 16);
    ((uint2*)agg16)[node * 32 + j8] = o;
  }
}

// ---------------- GEMM1: tmp16 = bf16(agg16 @ W1 + b1), stats1 ----------------
__global__ __launch_bounds__(256) void gemm1_kernel(
    const ushort_t* __restrict__ agg16, const short* __restrict__ Wp_hi,
    const short* __restrict__ Wp_lo, const float* __restrict__ bias,
    ushort_t* __restrict__ tmp16, float* __restrict__ stats_out) {
  __shared__ float sred[2 * CC];
  const int t = threadIdx.x;
  const int l = t & 63;
  const int wv = t >> 6;
  const int m0 = blockIdx.x * 64 + wv * 16;
  const int row = m0 + (l & 15);
  const int kg = (l >> 4) * 8;
  sred[t] = 0.f;

  f32x4 acc[8];
#pragma unroll
  for (int i = 0; i < 8; ++i) acc[i] = (f32x4){0.f, 0.f, 0.f, 0.f};

#pragma unroll
  for (int ks = 0; ks < 4; ++ks) {
    bf16x8 ah;
    if (row < NN) {
      ah = *(const bf16x8*)&agg16[row * CC + ks * 32 + kg];
    } else {
#pragma unroll
      for (int i = 0; i < 8; ++i) ah[i] = 0;
    }
#pragma unroll
    for (int nt = 0; nt < 8; ++nt) {
      const int base = (ks * 8 + nt) * 512 + l * 8;
      bf16x8 wh = *(const bf16x8*)&Wp_hi[base];
      bf16x8 wl = *(const bf16x8*)&Wp_lo[base];
      acc[nt] = __builtin_amdgcn_mfma_f32_16x16x32_bf16(ah, wh, acc[nt], 0, 0, 0);
      acc[nt] = __builtin_amdgcn_mfma_f32_16x16x32_bf16(ah, wl, acc[nt], 0, 0, 0);
    }
  }

  __syncthreads();
  const int rbase = m0 + (l >> 4) * 4;
  const int cn = l & 15;
#pragma unroll
  for (int nt = 0; nt < 8; ++nt) {
    int c = nt * 16 + cn;
    float bv = bias[c];
    float s = 0.f, qq = 0.f;
#pragma unroll
    for (int r = 0; r < 4; ++r) {
      int rr = rbase + r;
      if (rr < NN) {
        float v = acc[nt][r] + bv;
        tmp16[rr * CC + c] = f2bf(v);
        s += v; qq += v * v;
      }
    }
    s += __shfl_xor(s, 16); s += __shfl_xor(s, 32);
    qq += __shfl_xor(qq, 16); qq += __shfl_xor(qq, 32);
    if ((l >> 4) == 0) {
      atomicAdd(&sred[c], s);
      atomicAdd(&sred[CC + c], qq);
    }
  }
  __syncthreads();
  atomicAdd(&stats_out[t], sred[t]);
}

// ---------------- GEMM2: tmp16 = bf16(relu(BN1(tmp16)) @ W2 + b2) in-place, stats2 ----------------
__global__ __launch_bounds__(256) void gemm2_kernel(
    ushort_t* __restrict__ tmp16, const short* __restrict__ Wp_hi,
    const short* __restrict__ Wp_lo, const float* __restrict__ bias,
    const float* __restrict__ stats_in, const float* __restrict__ g,
    const float* __restrict__ be, float* __restrict__ stats_out) {
  __shared__ float sred[2 * CC];
  const int t = threadIdx.x;
  const int l = t & 63;
  const int wv = t >> 6;
  const int m0 = blockIdx.x * 64 + wv * 16;
  const int row = m0 + (l & 15);
  const int kg = (l >> 4) * 8;
  sred[t] = 0.f;

  f32x4 acc[8];
#pragma unroll
  for (int i = 0; i < 8; ++i) acc[i] = (f32x4){0.f, 0.f, 0.f, 0.f};

#pragma unroll
  for (int ks = 0; ks < 4; ++ks) {
    bf16x8 ah;
    if (row < NN) {
      bf16x8 raw = *(const bf16x8*)&tmp16[row * CC + ks * 32 + kg];
#pragma unroll
      for (int i = 0; i < 8; ++i) {
        int c = ks * 32 + kg + i;
        float mu = stats_in[c] * (1.0f / NN);
        float var = fmaxf(stats_in[CC + c] * (1.0f / NN) - mu * mu, 0.f);
        float a = g[c] * rsqrtf(var + BN_EPS);
        float d = fmaf(-mu, a, be[c]);
        float v = bf2f((unsigned)(ushort_t)raw[i]);
        v = fmaxf(fmaf(v, a, d), 0.f);
        ah[i] = (short)f2bf(v);
      }
    } else {
#pragma unroll
      for (int i = 0; i < 8; ++i) ah[i] = 0;
    }
#pragma unroll
    for (int nt = 0; nt < 8; ++nt) {
      const int base = (ks * 8 + nt) * 512 + l * 8;
      bf16x8 wh = *(const bf16x8*)&Wp_hi[base];
      bf16x8 wl = *(const bf16x8*)&Wp_lo[base];
      acc[nt] = __builtin_amdgcn_mfma_f32_16x16x32_bf16(ah, wh, acc[nt], 0, 0, 0);
      acc[nt] = __builtin_amdgcn_mfma_f32_16x16x32_bf16(ah, wl, acc[nt], 0, 0, 0);
    }
  }

  __syncthreads();
  const int rbase = m0 + (l >> 4) * 4;
  const int cn = l & 15;
#pragma unroll
  for (int nt = 0; nt < 8; ++nt) {
    int c = nt * 16 + cn;
    float bv = bias[c];
    float s = 0.f, qq = 0.f;
#pragma unroll
    for (int r = 0; r < 4; ++r) {
      int rr = rbase + r;
      if (rr < NN) {
        float v = acc[nt][r] + bv;
        tmp16[rr * CC + c] = f2bf(v);
        s += v; qq += v * v;
      }
    }
    s += __shfl_xor(s, 16); s += __shfl_xor(s, 32);
    qq += __shfl_xor(qq, 16); qq += __shfl_xor(qq, 32);
    if ((l >> 4) == 0) {
      atomicAdd(&sred[c], s);
      atomicAdd(&sred[CC + c], qq);
    }
  }
  __syncthreads();
  atomicAdd(&stats_out[t], sred[t]);
}

// ---------------- apply: BN2(inline)+relu -> fp32 out slab + linear h16 ----------------
__global__ __launch_bounds__(256) void apply_kernel(
    const ushort_t* __restrict__ t2, const float* __restrict__ stats2,
    const float* __restrict__ g2, const float* __restrict__ be2,
    float* __restrict__ outslab, ushort_t* __restrict__ h16) {
  __shared__ float bn[2 * CC];
  const int t = threadIdx.x;
  if (t < CC) {
    float mu = stats2[t] * (1.0f / NN);
    float var = fmaxf(stats2[CC + t] * (1.0f / NN) - mu * mu, 0.f);
    float a = g2[t] * rsqrtf(var + BN_EPS);
    bn[t] = a;
    bn[CC + t] = fmaf(-mu, a, be2[t]);
  }
  __syncthreads();

  const int idx = blockIdx.x * 256 + t;
  const int node = idx >> 2;
  if (node >= NN) return;
  const int c0 = (idx & 3) * 32;

  const uint4* tp = (const uint4*)(t2 + node * CC + c0);  // 64 B
  uint4 r[4];
#pragma unroll
  for (int i = 0; i < 4; ++i) r[i] = tp[i];

  float vo[32];
#pragma unroll
  for (int i = 0; i < 4; ++i) {
    unsigned ws[4] = {r[i].x, r[i].y, r[i].z, r[i].w};
#pragma unroll
    for (int j = 0; j < 4; ++j) {
      vo[i * 8 + 2 * j] = bf2f(ws[j] & 0xFFFFu);
      vo[i * 8 + 2 * j + 1] = bf2f(ws[j] >> 16);
    }
  }
#pragma unroll
  for (int j = 0; j < 32; ++j) {
    int c = c0 + j;
    vo[j] = fmaxf(fmaf(vo[j], bn[c], bn[CC + c]), 0.f);
  }
  float* op = &outslab[node * CC + c0];
#pragma unroll
  for (int j = 0; j < 8; ++j) {
    float4 v = make_float4(vo[4 * j], vo[4 * j + 1], vo[4 * j + 2], vo[4 * j + 3]);
    *(float4*)&op[4 * j] = v;
  }
  if (h16) {
    uint4* hp = (uint4*)(h16 + node * CC + c0);
#pragma unroll
    for (int i = 0; i < 4; ++i) {
      uint4 o;
      o.x = (unsigned)f2bf(vo[i * 8 + 0]) | ((unsigned)f2bf(vo[i * 8 + 1]) << 16);
      o.y = (unsigned)f2bf(vo[i * 8 + 2]) | ((unsigned)f2bf(vo[i * 8 + 3]) << 16);
      o.z = (unsigned)f2bf(vo[i * 8 + 4]) | ((unsigned)f2bf(vo[i * 8 + 5]) << 16);
      o.w = (unsigned)f2bf(vo[i * 8 + 6]) | ((unsigned)f2bf(vo[i * 8 + 7]) << 16);
      hp[i] = o;
    }
  }
}

// ---------------- launch ----------------
extern "C" void kernel_launch(void* const* d_in, const int* in_sizes, int n_in,
                              void* d_out, int out_size, void* d_ws, size_t ws_size,
                              hipStream_t stream) {
  const float* x    = (const float*)d_in[0];
  const int*   edge = (const int*)d_in[1];
  const float* fh_W = (const float*)d_in[3];
  const float* fh_b = (const float*)d_in[4];
  const float* W1   = (const float*)d_in[5];
  const float* b1   = (const float*)d_in[6];
  const float* g1   = (const float*)d_in[7];
  const float* be1  = (const float*)d_in[8];
  const float* W2   = (const float*)d_in[9];
  const float* b2   = (const float*)d_in[10];
  const float* g2   = (const float*)d_in[11];
  const float* be2  = (const float*)d_in[12];
  float* out = (float*)d_out;

  const int* src = edge;
  const int* dst = edge + NE;

  // workspace layout: [counts 50048][fill 50048][stats 1536f] zeroed together
  int* counts   = (int*)d_ws;
  int* fill     = counts + 50048;
  float* stats  = (float*)(fill + 50048);          // 6 x 256 floats
  int* starts   = (int*)(stats + 1536);            // 50048
  int* blocksum = starts + 50048;                  // 256
  int* bucket   = blocksum + 256;                  // 800000
  short* whi    = (short*)(bucket + NE);           // 7*16384
  short* wlo    = whi + 7 * CC * CC;               // 7*16384
  ushort_t* h16 = (ushort_t*)(wlo + 7 * CC * CC);  // SLAB bf16 (linear)
  ushort_t* agg16 = h16 + SLAB;                    // SLAB bf16 (linear)
  ushort_t* tmp16 = agg16 + SLAB;                  // SLAB bf16 (linear)

  // CSR build + stats zero
  zero_int_kernel<<<(101632 + 255) / 256, 256, 0, stream>>>(counts, 101632);
  count_kernel<<<NE / 256, 256, 0, stream>>>(dst, counts);
  scan1_kernel<<<196, 256, 0, stream>>>(counts, starts, blocksum);
  scan2_kernel<<<1, 256, 0, stream>>>(blocksum, 196);
  scan3_kernel<<<196, 256, 0, stream>>>(starts, blocksum);
  fill_kernel<<<NE / 256, 256, 0, stream>>>(src, dst, starts, fill, bucket);

  // weight prep
  prep_w_kernel<<<7, 256, 0, stream>>>(fh_W, W1, W2, whi, wlo);

  // first head
  gemm0_kernel<<<782, 256, 0, stream>>>(x, whi, wlo, fh_b, out, h16);

  for (int ly = 0; ly < 3; ++ly) {
    float* stats1 = stats + (ly * 2) * 256;
    float* stats2 = stats + (ly * 2 + 1) * 256;
    gather_kernel<<<NN / 4, 256, 0, stream>>>(h16, starts, counts, bucket, agg16);
    gemm1_kernel<<<782, 256, 0, stream>>>(
        agg16, whi + (1 + ly) * CC * CC, wlo + (1 + ly) * CC * CC, b1 + ly * CC, tmp16, stats1);
    gemm2_kernel<<<782, 256, 0, stream>>>(
        tmp16, whi + (4 + ly) * CC * CC, wlo + (4 + ly) * CC * CC, b2 + ly * CC,
        stats1, g1 + ly * CC, be1 + ly * CC, stats2);
    apply_kernel<<<782, 256, 0, stream>>>(
        tmp16, stats2, g2 + ly * CC, be2 + ly * CC, out + (ly + 1) * SLAB,
        (ly < 2) ? h16 : (ushort_t*)nullptr);
  }
}